// Round 7
// baseline (228.409 us; speedup 1.0000x reference)
//
#include <hip/hip_runtime.h>
#include <hip/hip_bf16.h>
#include <cstdint>
#include <cstddef>

typedef __bf16 bf16x8 __attribute__((ext_vector_type(8)));
typedef __bf16 bf16x4 __attribute__((ext_vector_type(4)));
typedef __bf16 bf16x2 __attribute__((ext_vector_type(2)));
typedef float  f32x4  __attribute__((ext_vector_type(4)));

static constexpr int TSEQ  = 2048;
static constexpr int DM    = 1024;
static constexpr int NH    = 16;
static constexpr int HD    = 64;
static constexpr int BATCH = 4;
// exp(s/8) = 2^(s * log2(e)/8)
static constexpr float SCL = 0.18033688011112042f;

// async global->LDS, 16B per lane; LDS dest is wave-uniform base + lane*16
__device__ __forceinline__ void gload16(const __bf16* g, __bf16* l) {
  __builtin_amdgcn_global_load_lds((const __attribute__((address_space(1))) void*)g,
                                   (__attribute__((address_space(3))) void*)l, 16, 0, 0);
}

#define PBAR()  asm volatile("s_barrier" ::: "memory")
#define LGKM()  asm volatile("s_waitcnt lgkmcnt(0)" ::: "memory")

// ---------------- fp32 -> bf16 convert ----------------
__global__ __launch_bounds__(256) void cvt_kernel(const float* __restrict__ in,
                                                  __bf16* __restrict__ out, int n4) {
  int i = blockIdx.x * 256 + threadIdx.x;
  if (i < n4) {
    float4 v = reinterpret_cast<const float4*>(in)[i];
    bf16x4 o;
    o[0] = (__bf16)v.x; o[1] = (__bf16)v.y; o[2] = (__bf16)v.z; o[3] = (__bf16)v.w;
    reinterpret_cast<bf16x4*>(out)[i] = o;
  }
}

// 4 weight matrices in one launch (blockIdx.y selects)
__global__ __launch_bounds__(256) void cvt4_kernel(
    const float* __restrict__ a, const float* __restrict__ bsrc,
    const float* __restrict__ c, const float* __restrict__ d,
    __bf16* __restrict__ oa, __bf16* __restrict__ ob,
    __bf16* __restrict__ oc, __bf16* __restrict__ od, int n4) {
  const float* src = (blockIdx.y == 0) ? a : (blockIdx.y == 1) ? bsrc
                    : (blockIdx.y == 2) ? c : d;
  __bf16* dst = (blockIdx.y == 0) ? oa : (blockIdx.y == 1) ? ob
               : (blockIdx.y == 2) ? oc : od;
  int i = blockIdx.x * 256 + threadIdx.x;
  if (i < n4) {
    float4 v = reinterpret_cast<const float4*>(src)[i];
    bf16x4 o;
    o[0] = (__bf16)v.x; o[1] = (__bf16)v.y; o[2] = (__bf16)v.z; o[3] = (__bf16)v.w;
    reinterpret_cast<bf16x4*>(dst)[i] = o;
  }
}

// ---------------- QKV GEMM body: 256x256, BK=64, 8 waves, 4-phase counted-vmcnt ----------------
// Wave (wr,wc) output = 4 scattered 64x32 strips. Phases as R6; the only change
// vs R6: no sched_barrier(0) after lgkmcnt (compiler-visible ds_reads -> let it
// schedule; rule 18 applies to inline-asm reads only).
template <typename OUT_T>
__device__ __forceinline__ void gemm_body8(
    const __bf16* __restrict__ A, const __bf16* __restrict__ W,
    const float* __restrict__ bias, OUT_T* __restrict__ C,
    int i0, int o0, __bf16* lA, __bf16* lB) {
  const int tid = threadIdx.x;          // 0..511
  const int l = tid & 63, lr = l & 15, lg = l >> 4;
  const int w = tid >> 6;
  const int wr = w >> 2, wc = w & 3;

  f32x4 acc[8][4];
  const f32x4 fzero = {0.f, 0.f, 0.f, 0.f};
#pragma unroll
  for (int mi = 0; mi < 8; ++mi)
#pragma unroll
    for (int ni = 0; ni < 4; ++ni) acc[mi][ni] = fzero;

  const int s_row = tid >> 3;           // 0..63
  const int s_cc  = tid & 7;
  const __bf16* Ab = A + (size_t)i0 * DM;
  const __bf16* Wb = W + (size_t)o0 * DM;

  auto stage = [&](const __bf16* G, __bf16* L, int buf, int kt, int h) {
#pragma unroll
    for (int rr = 0; rr < 2; ++rr) {
      int row = h * 128 + rr * 64 + s_row;
      gload16(G + (size_t)row * DM + kt * 64 + ((s_cc ^ (row & 7)) << 3),
              L + buf * 16384 + (h * 128 + rr * 64) * 64 + tid * 8);
    }
  };
  auto rd = [&](const __bf16* base, int row, int ks) {
    int chunk = (ks * 4 + lg) ^ (row & 7);
    return *(const bf16x8*)(base + row * 64 + chunk * 8);
  };

  const int NT = DM / 64;               // 16 K-tiles

  // prologue: tiles 0 and 1 fully staged; wait tile 0 (8 newest = tile 1)
#pragma unroll
  for (int h = 0; h < 2; ++h) { stage(Ab, lA, 0, 0, h); stage(Wb, lB, 0, 0, h); }
#pragma unroll
  for (int h = 0; h < 2; ++h) { stage(Ab, lA, 1, 1, h); stage(Wb, lB, 1, 1, h); }
  asm volatile("s_waitcnt vmcnt(8)" ::: "memory");
  PBAR();

  for (int t = 0; t < NT; ++t) {
    const int cur = t & 1;
    const __bf16* cA = lA + cur * 16384;
    const __bf16* cB = lB + cur * 16384;
    const bool pre = (t + 2 < NT);

    bf16x8 afl[4][2], bfl[2][2], afh[4][2], bfh[2][2];

    // ---- phase 1: mi-lo x ni-lo ----
#pragma unroll
    for (int mi = 0; mi < 4; ++mi)
#pragma unroll
      for (int ks = 0; ks < 2; ++ks)
        afl[mi][ks] = rd(cA, wr * 64 + mi * 16 + lr, ks);
#pragma unroll
    for (int ni = 0; ni < 2; ++ni)
#pragma unroll
      for (int ks = 0; ks < 2; ++ks)
        bfl[ni][ks] = rd(cB, wc * 32 + ni * 16 + lr, ks);
    PBAR(); LGKM();
    __builtin_amdgcn_s_setprio(1);
#pragma unroll
    for (int mi = 0; mi < 4; ++mi)
#pragma unroll
      for (int ni = 0; ni < 2; ++ni)
#pragma unroll
        for (int ks = 0; ks < 2; ++ks)
          acc[mi][ni] = __builtin_amdgcn_mfma_f32_16x16x32_bf16(
              afl[mi][ks], bfl[ni][ks], acc[mi][ni], 0, 0, 0);
    __builtin_amdgcn_s_setprio(0);
    PBAR();

    // ---- phase 2: mi-lo x ni-hi; stage Bh0(t+2) ----
#pragma unroll
    for (int ni = 0; ni < 2; ++ni)
#pragma unroll
      for (int ks = 0; ks < 2; ++ks)
        bfh[ni][ks] = rd(cB, 128 + wc * 32 + ni * 16 + lr, ks);
    if (pre) stage(Wb, lB, cur, t + 2, 0);
    PBAR(); LGKM();
    __builtin_amdgcn_s_setprio(1);
#pragma unroll
    for (int mi = 0; mi < 4; ++mi)
#pragma unroll
      for (int ni = 0; ni < 2; ++ni)
#pragma unroll
        for (int ks = 0; ks < 2; ++ks)
          acc[mi][ni + 2] = __builtin_amdgcn_mfma_f32_16x16x32_bf16(
              afl[mi][ks], bfh[ni][ks], acc[mi][ni + 2], 0, 0, 0);
    __builtin_amdgcn_s_setprio(0);
    PBAR();

    // ---- phase 3: mi-hi x ni-lo (bf_lo held); stage Ah0,Bh1(t+2) ----
#pragma unroll
    for (int mi = 0; mi < 4; ++mi)
#pragma unroll
      for (int ks = 0; ks < 2; ++ks)
        afh[mi][ks] = rd(cA, 128 + wr * 64 + mi * 16 + lr, ks);
    if (pre) { stage(Ab, lA, cur, t + 2, 0); stage(Wb, lB, cur, t + 2, 1); }
    PBAR(); LGKM();
    __builtin_amdgcn_s_setprio(1);
#pragma unroll
    for (int mi = 0; mi < 4; ++mi)
#pragma unroll
      for (int ni = 0; ni < 2; ++ni)
#pragma unroll
        for (int ks = 0; ks < 2; ++ks)
          acc[mi + 4][ni] = __builtin_amdgcn_mfma_f32_16x16x32_bf16(
              afh[mi][ks], bfl[ni][ks], acc[mi + 4][ni], 0, 0, 0);
    __builtin_amdgcn_s_setprio(0);
    PBAR();

    // ---- phase 4: mi-hi x ni-hi (held regs); stage Ah1(t+2); counted vmcnt ----
    if (pre) stage(Ab, lA, cur, t + 2, 1);
    if (pre)                asm volatile("s_waitcnt vmcnt(8)" ::: "memory");
    else if (t + 1 < NT)    asm volatile("s_waitcnt vmcnt(0)" ::: "memory");
    PBAR();
    __builtin_amdgcn_s_setprio(1);
#pragma unroll
    for (int mi = 0; mi < 4; ++mi)
#pragma unroll
      for (int ni = 0; ni < 2; ++ni)
#pragma unroll
        for (int ks = 0; ks < 2; ++ks)
          acc[mi + 4][ni + 2] = __builtin_amdgcn_mfma_f32_16x16x32_bf16(
              afh[mi][ks], bfh[ni][ks], acc[mi + 4][ni + 2], 0, 0, 0);
    __builtin_amdgcn_s_setprio(0);
    PBAR();
  }

#pragma unroll
  for (int ni = 0; ni < 4; ++ni) {
    int colb = (ni < 2) ? (wc * 32 + ni * 16) : (128 + wc * 32 + (ni - 2) * 16);
    int col = o0 + colb + lr;
    float bb = bias[col];
#pragma unroll
    for (int mi = 0; mi < 8; ++mi) {
      int rowb = (mi < 4) ? (wr * 64 + mi * 16) : (128 + wr * 64 + (mi - 4) * 16);
      int row = i0 + rowb + lg * 4;
#pragma unroll
      for (int r = 0; r < 4; ++r)
        C[(size_t)(row + r) * DM + col] = (OUT_T)(acc[mi][ni][r] + bb);
    }
  }
}

// QKV fused over N=3072: grid 384 = 32 mi * 12 nig (256x256 tiles), XCD-grouped.
__global__ __launch_bounds__(512, 2) void gemm_qkv_kernel(
    const __bf16* __restrict__ A,
    const __bf16* __restrict__ W0, const __bf16* __restrict__ W1,
    const __bf16* __restrict__ W2,
    const float* __restrict__ b0, const float* __restrict__ b1,
    const float* __restrict__ b2,
    __bf16* __restrict__ O0, __bf16* __restrict__ O1, __bf16* __restrict__ O2) {
  __shared__ __align__(16) __bf16 lA[2 * 256 * 64];
  __shared__ __align__(16) __bf16 lB[2 * 256 * 64];
  const int flat = blockIdx.x;
  const int xcd = flat & 7, idx = flat >> 3;       // idx 0..47
  const int mi = xcd * 4 + idx / 12;               // 0..31
  const int nig = idx % 12;                        // 0..11
  const int z = nig >> 2;
  const int o0 = (nig & 3) * 256;
  const __bf16* W = (z == 0) ? W0 : (z == 1) ? W1 : W2;
  const float* bias = (z == 0) ? b0 : (z == 1) ? b1 : b2;
  __bf16* C = (z == 0) ? O0 : (z == 1) ? O1 : O2;
  gemm_body8<__bf16>(A, W, bias, C, mi * 256, o0, lA, lB);
}

// ---------------- out-proj GEMM: 128x256 tile (R4 body), grid 256 ----------------
template <typename OUT_T>
__device__ __forceinline__ void gemm_body2(
    const __bf16* __restrict__ A, const __bf16* __restrict__ W,
    const float* __restrict__ bias, OUT_T* __restrict__ C,
    int i0, int o0, __bf16* lA, __bf16* lB) {
  const int tid = threadIdx.x;          // 0..511
  const int l = tid & 63, lr = l & 15, lg = l >> 4;
  const int w = tid >> 6;
  const int wr = w >> 2, wc = w & 3;

  f32x4 acc[4][4];
  const f32x4 fzero = {0.f, 0.f, 0.f, 0.f};
#pragma unroll
  for (int mi = 0; mi < 4; ++mi)
#pragma unroll
    for (int ni = 0; ni < 4; ++ni) acc[mi][ni] = fzero;

  const int s_row = tid >> 3;
  const int s_cc  = tid & 7;
  const int NT = DM / 64;  // 16

  {
#pragma unroll
    for (int n = 0; n < 2; ++n) {
      int row = n * 64 + s_row;
      gload16(A + (size_t)(i0 + row) * DM + ((s_cc ^ (row & 7)) << 3),
              lA + n * 4096 + tid * 8);
    }
#pragma unroll
    for (int n = 0; n < 4; ++n) {
      int row = n * 64 + s_row;
      gload16(W + (size_t)(o0 + row) * DM + ((s_cc ^ (row & 7)) << 3),
              lB + n * 4096 + tid * 8);
    }
  }
  asm volatile("s_waitcnt vmcnt(0)" ::: "memory");
  __syncthreads();

  for (int t = 0; t < NT; ++t) {
    const int cur = t & 1;
    if (t + 1 < NT) {
      const int k0 = (t + 1) * 64;
      const int nxt = cur ^ 1;
#pragma unroll
      for (int n = 0; n < 2; ++n) {
        int row = n * 64 + s_row;
        gload16(A + (size_t)(i0 + row) * DM + k0 + ((s_cc ^ (row & 7)) << 3),
                lA + nxt * 8192 + n * 4096 + tid * 8);
      }
#pragma unroll
      for (int n = 0; n < 4; ++n) {
        int row = n * 64 + s_row;
        gload16(W + (size_t)(o0 + row) * DM + k0 + ((s_cc ^ (row & 7)) << 3),
                lB + nxt * 16384 + n * 4096 + tid * 8);
      }
    }

    const __bf16* cA = lA + cur * 8192;
    const __bf16* cB = lB + cur * 16384;

    bf16x8 af[4][2], bf_[2][2];
#pragma unroll
    for (int mi = 0; mi < 4; ++mi)
#pragma unroll
      for (int ks = 0; ks < 2; ++ks) {
        int row = wr * 64 + mi * 16 + lr;
        int chunk = (ks * 4 + lg) ^ (row & 7);
        af[mi][ks] = *(const bf16x8*)(cA + row * 64 + chunk * 8);
      }
#pragma unroll
    for (int ni = 0; ni < 2; ++ni)
#pragma unroll
      for (int ks = 0; ks < 2; ++ks) {
        int row = wc * 64 + ni * 16 + lr;
        int chunk = (ks * 4 + lg) ^ (row & 7);
        bf_[ni][ks] = *(const bf16x8*)(cB + row * 64 + chunk * 8);
      }
    __builtin_amdgcn_s_setprio(1);
#pragma unroll
    for (int mi = 0; mi < 4; ++mi)
#pragma unroll
      for (int ni = 0; ni < 2; ++ni)
#pragma unroll
        for (int ks = 0; ks < 2; ++ks)
          acc[mi][ni] = __builtin_amdgcn_mfma_f32_16x16x32_bf16(
              af[mi][ks], bf_[ni][ks], acc[mi][ni], 0, 0, 0);
    __builtin_amdgcn_s_setprio(0);

#pragma unroll
    for (int ni = 0; ni < 2; ++ni)
#pragma unroll
      for (int ks = 0; ks < 2; ++ks) {
        int row = wc * 64 + (ni + 2) * 16 + lr;
        int chunk = (ks * 4 + lg) ^ (row & 7);
        bf_[ni][ks] = *(const bf16x8*)(cB + row * 64 + chunk * 8);
      }
    __builtin_amdgcn_s_setprio(1);
#pragma unroll
    for (int mi = 0; mi < 4; ++mi)
#pragma unroll
      for (int ni = 0; ni < 2; ++ni)
#pragma unroll
        for (int ks = 0; ks < 2; ++ks)
          acc[mi][ni + 2] = __builtin_amdgcn_mfma_f32_16x16x32_bf16(
              af[mi][ks], bf_[ni][ks], acc[mi][ni + 2], 0, 0, 0);
    __builtin_amdgcn_s_setprio(0);

    if (t + 1 < NT) {
      asm volatile("s_waitcnt vmcnt(0)" ::: "memory");
      __syncthreads();
    }
  }

#pragma unroll
  for (int ni = 0; ni < 4; ++ni) {
    int col = o0 + wc * 64 + ni * 16 + lr;
    float bb = bias[col];
#pragma unroll
    for (int mi = 0; mi < 4; ++mi) {
      int row = i0 + wr * 64 + mi * 16 + lg * 4;
#pragma unroll
      for (int r = 0; r < 4; ++r)
        C[(size_t)(row + r) * DM + col] = (OUT_T)(acc[mi][ni][r] + bb);
    }
  }
}

// Output GEMM: grid 256 = 64 mi * 4 ni (exactly 1 block/CU), XCD-grouped.
__global__ __launch_bounds__(512, 2) void gemm_out_kernel(
    const __bf16* __restrict__ A, const __bf16* __restrict__ W,
    const float* __restrict__ bias, float* __restrict__ C) {
  __shared__ __align__(16) __bf16 lA[2 * 128 * 64];
  __shared__ __align__(16) __bf16 lB[2 * 256 * 64];
  const int flat = blockIdx.x;
  const int xcd = flat & 7, idx = flat >> 3;       // idx 0..31
  const int mi = xcd * 8 + (idx & 7);              // 0..63
  const int ni = idx >> 3;                         // 0..3
  gemm_body2<float>(A, W, bias, C, mi * 128, ni * 256, lA, lB);
}

// ---------------- pass B: column sums c[k] = sum_{q>=k} exp(s[q,k]); VT = V^T / c ----------------
// flat grid 1024; XCD-grouped so a (b,h) group's 16 blocks share one XCD L2;
// k-tile pairing {bx, 31-bx} makes per-block work constant (132 chunks).
__global__ __launch_bounds__(256) void colstats_kernel(
    const __bf16* __restrict__ Q, const __bf16* __restrict__ K,
    const __bf16* __restrict__ V, __bf16* __restrict__ VT) {
  const int flat = blockIdx.x;
  const int wid = (flat & 7) * 128 + (flat >> 3);  // 0..1023
  const int g = wid >> 4, bx = wid & 15;
  const int h = g & 15, b = g >> 4;
  const int tid = threadIdx.x;
  const int w = tid >> 6, l = tid & 63, lr = l & 15, lg = l >> 4;
  const size_t base = (size_t)b * TSEQ * DM + (size_t)h * HD;

  __shared__ float part[4][64];
  __shared__ float invc[64];

  for (int ph = 0; ph < 2; ++ph) {
    const int kt = ph ? (31 - bx) : bx;
    const int k0 = kt * 64;

    bf16x8 kf[4][2];
#pragma unroll
    for (int ct = 0; ct < 4; ++ct)
#pragma unroll
      for (int ks = 0; ks < 2; ++ks)
        kf[ct][ks] = *(const bf16x8*)(K + base + (size_t)(k0 + ct * 16 + lr) * DM +
                                      ks * 32 + lg * 8);

    float csum[4] = {0.f, 0.f, 0.f, 0.f};
    const int nchunks = (TSEQ - k0) >> 4;  // >= 4 always
    for (int jj = w; jj < nchunks; jj += 4) {
      int qrow = k0 + jj * 16;
      bf16x8 a0 = *(const bf16x8*)(Q + base + (size_t)(qrow + lr) * DM + lg * 8);
      bf16x8 a1 = *(const bf16x8*)(Q + base + (size_t)(qrow + lr) * DM + 32 + lg * 8);
      const bool interior = (jj >= 4);  // whole chunk strictly below diagonal band
#pragma unroll
      for (int ct = 0; ct < 4; ++ct) {
        f32x4 s = {0.f, 0.f, 0.f, 0.f};
        s = __builtin_amdgcn_mfma_f32_16x16x32_bf16(a0, kf[ct][0], s, 0, 0, 0);
        s = __builtin_amdgcn_mfma_f32_16x16x32_bf16(a1, kf[ct][1], s, 0, 0, 0);
        if (interior) {
#pragma unroll
          for (int r = 0; r < 4; ++r) csum[ct] += __builtin_amdgcn_exp2f(s[r] * SCL);
        } else {
#pragma unroll
          for (int r = 0; r < 4; ++r) {
            int ql = jj * 16 + lg * 4 + r;
            int kl = ct * 16 + lr;
            float e = __builtin_amdgcn_exp2f(s[r] * SCL);
            csum[ct] += (ql >= kl) ? e : 0.f;
          }
        }
      }
    }

#pragma unroll
    for (int ct = 0; ct < 4; ++ct) {
      csum[ct] += __shfl_xor(csum[ct], 16, 64);
      csum[ct] += __shfl_xor(csum[ct], 32, 64);
    }

    if (l < 16) {
#pragma unroll
      for (int ct = 0; ct < 4; ++ct) part[w][ct * 16 + l] = csum[ct];
    }
    __syncthreads();
    if (tid < 64) {
      float c = part[0][tid] + part[1][tid] + part[2][tid] + part[3][tid];
      invc[tid] = 1.0f / c;
    }
    __syncthreads();

    // VT[b,h][d][k] = V[k][d] * invc ; thread t: d = t>>2, k-cols (t&3)*16..+15
    const int d = tid >> 2, gq = tid & 3;
    size_t vtb = (((size_t)(b * NH + h)) * HD + d) * TSEQ + k0 + gq * 16;
#pragma unroll
    for (int kc = 0; kc < 16; kc += 2) {
      int kl = gq * 16 + kc;
      float v0 = (float)V[base + (size_t)(k0 + kl) * DM + d] * invc[kl];
      float v1 = (float)V[base + (size_t)(k0 + kl + 1) * DM + d] * invc[kl + 1];
      bf16x2 o; o[0] = (__bf16)v0; o[1] = (__bf16)v1;
      *(bf16x2*)(VT + vtb + kc) = o;
    }
    __syncthreads();  // part/invc reuse safety across phases
  }
}

// XOR swizzle (involution) on element index of a [64][64] bf16 tile
__device__ __forceinline__ int swz(int e) { return e ^ (((e >> 6) & 7) << 3); }

// ---------------- pass C: ctx[q,:] = sum_{k<=q} exp(s[q,k]) * VT[:,k] ----------------
// flat grid 1024, XCD-grouped; q-tile pairing {31-bx, bx} -> 33 K-steps/block.
// NOW double-buffered: issue K/V tile t+1 BEFORE computing tile t, drain after
// (hides L2/HBM latency under QK+P+PV compute). LDS 43 KB -> 3 blocks/CU.
__global__ __launch_bounds__(256) void ctx_kernel(
    const __bf16* __restrict__ Q, const __bf16* __restrict__ K,
    const __bf16* __restrict__ VT, __bf16* __restrict__ CTX) {
  __shared__ __align__(16) __bf16 lK[2][4096];
  __shared__ __align__(16) __bf16 lV[2][4096];
  __shared__ __align__(16) __bf16 lP[4][16 * 88];
  const int flat = blockIdx.x;
  const int wid = (flat & 7) * 128 + (flat >> 3);  // 0..1023
  const int g = wid >> 4, bx = wid & 15;
  const int h = g & 15, b = g >> 4;
  const int tid = threadIdx.x;
  const int w = tid >> 6, l = tid & 63, lr = l & 15, lg = l >> 4;
  const size_t base = (size_t)b * TSEQ * DM + (size_t)h * HD;
  const size_t vtb = ((size_t)(b * NH + h)) * HD * TSEQ;
  __bf16* pw = &lP[w][0];

  // gload source decomposition: LDS element e = n*2048 + w*512 + l*8
  // -> tile row = n*32 + srow, source col pre-swizzled by (row&7)
  const int srow = w * 8 + (l >> 3);
  const int scol = (((l & 7) ^ (l >> 3)) << 3);

  auto stageKV = [&](int kt, int buf) {
    const int k0 = kt * 64;
#pragma unroll
    for (int n = 0; n < 2; ++n) {
      gload16(K + base + (size_t)(k0 + n * 32 + srow) * DM + scol,
              &lK[buf][0] + n * 2048 + w * 512);
      gload16(VT + vtb + (size_t)(n * 32 + srow) * TSEQ + k0 + scol,
              &lV[buf][0] + n * 2048 + w * 512);
    }
  };

  for (int ph = 0; ph < 2; ++ph) {
    const int qt = ph ? bx : 31 - bx;
    const int q0 = qt * 64;

    bf16x8 qf[2];
#pragma unroll
    for (int ks = 0; ks < 2; ++ks)
      qf[ks] = *(const bf16x8*)(Q + base + (size_t)(q0 + w * 16 + lr) * DM + ks * 32 + lg * 8);

    f32x4 acc[4];
    const f32x4 fzero = {0.f, 0.f, 0.f, 0.f};
#pragma unroll
    for (int dt = 0; dt < 4; ++dt) acc[dt] = fzero;

    // phase boundary: all prior-phase LDS reads done before restaging buf 0
    __syncthreads();
    stageKV(0, 0);
    asm volatile("s_waitcnt vmcnt(0)" ::: "memory");
    __syncthreads();

    for (int kt = 0; kt <= qt; ++kt) {
      const int cur = kt & 1;
      if (kt < qt) stageKV(kt + 1, cur ^ 1);  // issue-early: lands under compute

      const __bf16* cK = &lK[cur][0];
      const __bf16* cV = &lV[cur][0];
      const bool diag = (kt == qt);
#pragma unroll
      for (int ct = 0; ct < 4; ++ct) {
        f32x4 s = {0.f, 0.f, 0.f, 0.f};
#pragma unroll
        for (int ks = 0; ks < 2; ++ks) {
          int e = (ct * 16 + lr) * 64 + ks * 32 + lg * 8;
          bf16x8 kb8 = *(const bf16x8*)(cK + swz(e));
          // swapped: A = K rows (-> D rows = k), B = Q (-> D cols = q)
          s = __builtin_amdgcn_mfma_f32_16x16x32_bf16(kb8, qf[ks], s, 0, 0, 0);
        }
        bf16x4 pk;
        if (diag) {
#pragma unroll
          for (int r = 0; r < 4; ++r) {
            int ql = w * 16 + lr;            // local q (tile-relative)
            int kl = ct * 16 + lg * 4 + r;   // local k (same tile on diag)
            float pv = (ql >= kl) ? __builtin_amdgcn_exp2f(s[r] * SCL) : 0.f;
            pk[r] = (__bf16)pv;
          }
        } else {
#pragma unroll
          for (int r = 0; r < 4; ++r)
            pk[r] = (__bf16)__builtin_amdgcn_exp2f(s[r] * SCL);
        }
        // P[q=lr][k = ct*16 + lg*4 .. +3] -> one b64 write
        *(bf16x4*)(pw + lr * 88 + ct * 16 + lg * 4) = pk;
      }
      asm volatile("" ::: "memory");  // same-wave DS in-order: writes before reads

      bf16x8 pa[2];
#pragma unroll
      for (int ks = 0; ks < 2; ++ks)
        pa[ks] = *(const bf16x8*)(pw + lr * 88 + ks * 32 + lg * 8);
#pragma unroll
      for (int dt = 0; dt < 4; ++dt) {
#pragma unroll
        for (int ks = 0; ks < 2; ++ks) {
          int e = (dt * 16 + lr) * 64 + ks * 32 + lg * 8;
          bf16x8 vb8 = *(const bf16x8*)(cV + swz(e));
          acc[dt] = __builtin_amdgcn_mfma_f32_16x16x32_bf16(pa[ks], vb8, acc[dt], 0, 0, 0);
        }
      }

      if (kt < qt) {
        // drain next tile's loads AFTER this tile's compute; barrier publishes
        // buf cur^1 and confirms buf cur's readers are done (for kt+2's stage).
        asm volatile("s_waitcnt vmcnt(0)" ::: "memory");
        __syncthreads();
      }
    }

#pragma unroll
    for (int dt = 0; dt < 4; ++dt)
#pragma unroll
      for (int r = 0; r < 4; ++r)
        CTX[base + (size_t)(q0 + w * 16 + lg * 4 + r) * DM + dt * 16 + lr] = (__bf16)acc[dt][r];
  }
}

extern "C" void kernel_launch(void* const* d_in, const int* in_sizes, int n_in,
                              void* d_out, int out_size, void* d_ws, size_t ws_size,
                              hipStream_t stream) {
  const float* q  = (const float*)d_in[0];
  const float* Wq = (const float*)d_in[3];
  const float* bq = (const float*)d_in[4];
  const float* Wk = (const float*)d_in[5];
  const float* bk = (const float*)d_in[6];
  const float* Wv = (const float*)d_in[7];
  const float* bv = (const float*)d_in[8];
  const float* Wo = (const float*)d_in[9];
  const float* bo = (const float*)d_in[10];
  float* out = (float*)d_out;

  const size_t NTOK = (size_t)BATCH * TSEQ;  // 8192
  char* ws = (char*)d_ws;
  __bf16* qb  = (__bf16*)ws; ws += NTOK * DM * 2;   // reused as CTX after QKV GEMMs
  __bf16* Wqb = (__bf16*)ws; ws += (size_t)DM * DM * 2;
  __bf16* Wkb = (__bf16*)ws; ws += (size_t)DM * DM * 2;
  __bf16* Wvb = (__bf16*)ws; ws += (size_t)DM * DM * 2;
  __bf16* Wob = (__bf16*)ws; ws += (size_t)DM * DM * 2;
  __bf16* Qp  = (__bf16*)ws; ws += NTOK * DM * 2;
  __bf16* Kp  = (__bf16*)ws; ws += NTOK * DM * 2;
  __bf16* Vp  = (__bf16*)ws; ws += NTOK * DM * 2;
  __bf16* VT  = (__bf16*)ws; ws += (size_t)BATCH * NH * HD * TSEQ * 2;
  __bf16* CTX = qb;  // qb dead after the QKV GEMMs

  const int nq4 = (int)(NTOK * DM / 4);
  const int nw4 = DM * DM / 4;
  cvt_kernel<<<(nq4 + 255) / 256, 256, 0, stream>>>(q, qb, nq4);
  cvt4_kernel<<<dim3((nw4 + 255) / 256, 4), 256, 0, stream>>>(
      Wq, Wk, Wv, Wo, Wqb, Wkb, Wvb, Wob, nw4);

  gemm_qkv_kernel<<<384, 512, 0, stream>>>(qb, Wqb, Wkb, Wvb, bq, bk, bv,
                                           Qp, Kp, Vp);

  colstats_kernel<<<1024, 256, 0, stream>>>(Qp, Kp, Vp, VT);
  ctx_kernel<<<1024, 256, 0, stream>>>(Qp, Kp, VT, CTX);

  gemm_out_kernel<<<256, 512, 0, stream>>>(CTX, Wob, bo, out);
}

// Round 8
// 208.702 us; speedup vs baseline: 1.0944x; 1.0944x over previous
//
#include <hip/hip_runtime.h>
#include <hip/hip_bf16.h>
#include <cstdint>
#include <cstddef>

typedef __bf16 bf16x8 __attribute__((ext_vector_type(8)));
typedef __bf16 bf16x4 __attribute__((ext_vector_type(4)));
typedef __bf16 bf16x2 __attribute__((ext_vector_type(2)));
typedef float  f32x4  __attribute__((ext_vector_type(4)));

static constexpr int TSEQ  = 2048;
static constexpr int DM    = 1024;
static constexpr int NH    = 16;
static constexpr int HD    = 64;
static constexpr int BATCH = 4;
// exp(s/8) = 2^(s * log2(e)/8)
static constexpr float SCL = 0.18033688011112042f;

// async global->LDS, 16B per lane; LDS dest is wave-uniform base + lane*16
__device__ __forceinline__ void gload16(const __bf16* g, __bf16* l) {
  __builtin_amdgcn_global_load_lds((const __attribute__((address_space(1))) void*)g,
                                   (__attribute__((address_space(3))) void*)l, 16, 0, 0);
}

#define PBAR()  asm volatile("s_barrier" ::: "memory")
#define LGKM()  asm volatile("s_waitcnt lgkmcnt(0)" ::: "memory")

// ---------------- fp32 -> bf16 convert ----------------
__global__ __launch_bounds__(256) void cvt_kernel(const float* __restrict__ in,
                                                  __bf16* __restrict__ out, int n4) {
  int i = blockIdx.x * 256 + threadIdx.x;
  if (i < n4) {
    float4 v = reinterpret_cast<const float4*>(in)[i];
    bf16x4 o;
    o[0] = (__bf16)v.x; o[1] = (__bf16)v.y; o[2] = (__bf16)v.z; o[3] = (__bf16)v.w;
    reinterpret_cast<bf16x4*>(out)[i] = o;
  }
}

// 4 weight matrices in one launch (blockIdx.y selects)
__global__ __launch_bounds__(256) void cvt4_kernel(
    const float* __restrict__ a, const float* __restrict__ bsrc,
    const float* __restrict__ c, const float* __restrict__ d,
    __bf16* __restrict__ oa, __bf16* __restrict__ ob,
    __bf16* __restrict__ oc, __bf16* __restrict__ od, int n4) {
  const float* src = (blockIdx.y == 0) ? a : (blockIdx.y == 1) ? bsrc
                    : (blockIdx.y == 2) ? c : d;
  __bf16* dst = (blockIdx.y == 0) ? oa : (blockIdx.y == 1) ? ob
               : (blockIdx.y == 2) ? oc : od;
  int i = blockIdx.x * 256 + threadIdx.x;
  if (i < n4) {
    float4 v = reinterpret_cast<const float4*>(src)[i];
    bf16x4 o;
    o[0] = (__bf16)v.x; o[1] = (__bf16)v.y; o[2] = (__bf16)v.z; o[3] = (__bf16)v.w;
    reinterpret_cast<bf16x4*>(dst)[i] = o;
  }
}

// ---------------- QKV GEMM body: 256x256, BK=64, 8 waves, 4-phase counted-vmcnt ----------------
// (unchanged from R6 — 70.5 us, MfmaUtil 29%)
template <typename OUT_T>
__device__ __forceinline__ void gemm_body8(
    const __bf16* __restrict__ A, const __bf16* __restrict__ W,
    const float* __restrict__ bias, OUT_T* __restrict__ C,
    int i0, int o0, __bf16* lA, __bf16* lB) {
  const int tid = threadIdx.x;          // 0..511
  const int l = tid & 63, lr = l & 15, lg = l >> 4;
  const int w = tid >> 6;
  const int wr = w >> 2, wc = w & 3;

  f32x4 acc[8][4];
  const f32x4 fzero = {0.f, 0.f, 0.f, 0.f};
#pragma unroll
  for (int mi = 0; mi < 8; ++mi)
#pragma unroll
    for (int ni = 0; ni < 4; ++ni) acc[mi][ni] = fzero;

  const int s_row = tid >> 3;           // 0..63
  const int s_cc  = tid & 7;
  const __bf16* Ab = A + (size_t)i0 * DM;
  const __bf16* Wb = W + (size_t)o0 * DM;

  auto stage = [&](const __bf16* G, __bf16* L, int buf, int kt, int h) {
#pragma unroll
    for (int rr = 0; rr < 2; ++rr) {
      int row = h * 128 + rr * 64 + s_row;
      gload16(G + (size_t)row * DM + kt * 64 + ((s_cc ^ (row & 7)) << 3),
              L + buf * 16384 + (h * 128 + rr * 64) * 64 + tid * 8);
    }
  };
  auto rd = [&](const __bf16* base, int row, int ks) {
    int chunk = (ks * 4 + lg) ^ (row & 7);
    return *(const bf16x8*)(base + row * 64 + chunk * 8);
  };

  const int NT = DM / 64;               // 16 K-tiles

  // prologue: tiles 0 and 1 fully staged; wait tile 0 (8 newest = tile 1)
#pragma unroll
  for (int h = 0; h < 2; ++h) { stage(Ab, lA, 0, 0, h); stage(Wb, lB, 0, 0, h); }
#pragma unroll
  for (int h = 0; h < 2; ++h) { stage(Ab, lA, 1, 1, h); stage(Wb, lB, 1, 1, h); }
  asm volatile("s_waitcnt vmcnt(8)" ::: "memory");
  PBAR();

  for (int t = 0; t < NT; ++t) {
    const int cur = t & 1;
    const __bf16* cA = lA + cur * 16384;
    const __bf16* cB = lB + cur * 16384;
    const bool pre = (t + 2 < NT);

    bf16x8 afl[4][2], bfl[2][2], afh[4][2], bfh[2][2];

    // ---- phase 1: mi-lo x ni-lo ----
#pragma unroll
    for (int mi = 0; mi < 4; ++mi)
#pragma unroll
      for (int ks = 0; ks < 2; ++ks)
        afl[mi][ks] = rd(cA, wr * 64 + mi * 16 + lr, ks);
#pragma unroll
    for (int ni = 0; ni < 2; ++ni)
#pragma unroll
      for (int ks = 0; ks < 2; ++ks)
        bfl[ni][ks] = rd(cB, wc * 32 + ni * 16 + lr, ks);
    PBAR(); LGKM();
    __builtin_amdgcn_s_setprio(1);
#pragma unroll
    for (int mi = 0; mi < 4; ++mi)
#pragma unroll
      for (int ni = 0; ni < 2; ++ni)
#pragma unroll
        for (int ks = 0; ks < 2; ++ks)
          acc[mi][ni] = __builtin_amdgcn_mfma_f32_16x16x32_bf16(
              afl[mi][ks], bfl[ni][ks], acc[mi][ni], 0, 0, 0);
    __builtin_amdgcn_s_setprio(0);
    PBAR();

    // ---- phase 2: mi-lo x ni-hi; stage Bh0(t+2) ----
#pragma unroll
    for (int ni = 0; ni < 2; ++ni)
#pragma unroll
      for (int ks = 0; ks < 2; ++ks)
        bfh[ni][ks] = rd(cB, 128 + wc * 32 + ni * 16 + lr, ks);
    if (pre) stage(Wb, lB, cur, t + 2, 0);
    PBAR(); LGKM();
    __builtin_amdgcn_s_setprio(1);
#pragma unroll
    for (int mi = 0; mi < 4; ++mi)
#pragma unroll
      for (int ni = 0; ni < 2; ++ni)
#pragma unroll
        for (int ks = 0; ks < 2; ++ks)
          acc[mi][ni + 2] = __builtin_amdgcn_mfma_f32_16x16x32_bf16(
              afl[mi][ks], bfh[ni][ks], acc[mi][ni + 2], 0, 0, 0);
    __builtin_amdgcn_s_setprio(0);
    PBAR();

    // ---- phase 3: mi-hi x ni-lo (bf_lo held); stage Ah0,Bh1(t+2) ----
#pragma unroll
    for (int mi = 0; mi < 4; ++mi)
#pragma unroll
      for (int ks = 0; ks < 2; ++ks)
        afh[mi][ks] = rd(cA, 128 + wr * 64 + mi * 16 + lr, ks);
    if (pre) { stage(Ab, lA, cur, t + 2, 0); stage(Wb, lB, cur, t + 2, 1); }
    PBAR(); LGKM();
    __builtin_amdgcn_s_setprio(1);
#pragma unroll
    for (int mi = 0; mi < 4; ++mi)
#pragma unroll
      for (int ni = 0; ni < 2; ++ni)
#pragma unroll
        for (int ks = 0; ks < 2; ++ks)
          acc[mi + 4][ni] = __builtin_amdgcn_mfma_f32_16x16x32_bf16(
              afh[mi][ks], bfl[ni][ks], acc[mi + 4][ni], 0, 0, 0);
    __builtin_amdgcn_s_setprio(0);
    PBAR();

    // ---- phase 4: mi-hi x ni-hi (held regs); stage Ah1(t+2); counted vmcnt ----
    if (pre) stage(Ab, lA, cur, t + 2, 1);
    if (pre)                asm volatile("s_waitcnt vmcnt(8)" ::: "memory");
    else if (t + 1 < NT)    asm volatile("s_waitcnt vmcnt(0)" ::: "memory");
    PBAR();
    __builtin_amdgcn_s_setprio(1);
#pragma unroll
    for (int mi = 0; mi < 4; ++mi)
#pragma unroll
      for (int ni = 0; ni < 2; ++ni)
#pragma unroll
        for (int ks = 0; ks < 2; ++ks)
          acc[mi + 4][ni + 2] = __builtin_amdgcn_mfma_f32_16x16x32_bf16(
              afh[mi][ks], bfh[ni][ks], acc[mi + 4][ni + 2], 0, 0, 0);
    __builtin_amdgcn_s_setprio(0);
    PBAR();
  }

#pragma unroll
  for (int ni = 0; ni < 4; ++ni) {
    int colb = (ni < 2) ? (wc * 32 + ni * 16) : (128 + wc * 32 + (ni - 2) * 16);
    int col = o0 + colb + lr;
    float bb = bias[col];
#pragma unroll
    for (int mi = 0; mi < 8; ++mi) {
      int rowb = (mi < 4) ? (wr * 64 + mi * 16) : (128 + wr * 64 + (mi - 4) * 16);
      int row = i0 + rowb + lg * 4;
#pragma unroll
      for (int r = 0; r < 4; ++r)
        C[(size_t)(row + r) * DM + col] = (OUT_T)(acc[mi][ni][r] + bb);
    }
  }
}

// QKV fused over N=3072: grid 384 = 32 mi * 12 nig (256x256 tiles), XCD-grouped.
__global__ __launch_bounds__(512, 2) void gemm_qkv_kernel(
    const __bf16* __restrict__ A,
    const __bf16* __restrict__ W0, const __bf16* __restrict__ W1,
    const __bf16* __restrict__ W2,
    const float* __restrict__ b0, const float* __restrict__ b1,
    const float* __restrict__ b2,
    __bf16* __restrict__ O0, __bf16* __restrict__ O1, __bf16* __restrict__ O2) {
  __shared__ __align__(16) __bf16 lA[2 * 256 * 64];
  __shared__ __align__(16) __bf16 lB[2 * 256 * 64];
  const int flat = blockIdx.x;
  const int xcd = flat & 7, idx = flat >> 3;       // idx 0..47
  const int mi = xcd * 4 + idx / 12;               // 0..31
  const int nig = idx % 12;                        // 0..11
  const int z = nig >> 2;
  const int o0 = (nig & 3) * 256;
  const __bf16* W = (z == 0) ? W0 : (z == 1) ? W1 : W2;
  const float* bias = (z == 0) ? b0 : (z == 1) ? b1 : b2;
  __bf16* C = (z == 0) ? O0 : (z == 1) ? O1 : O2;
  gemm_body8<__bf16>(A, W, bias, C, mi * 256, o0, lA, lB);
}

// ---------------- out-proj GEMM: 128x256 tile (R4 body), grid 256 ----------------
template <typename OUT_T>
__device__ __forceinline__ void gemm_body2(
    const __bf16* __restrict__ A, const __bf16* __restrict__ W,
    const float* __restrict__ bias, OUT_T* __restrict__ C,
    int i0, int o0, __bf16* lA, __bf16* lB) {
  const int tid = threadIdx.x;          // 0..511
  const int l = tid & 63, lr = l & 15, lg = l >> 4;
  const int w = tid >> 6;
  const int wr = w >> 2, wc = w & 3;

  f32x4 acc[4][4];
  const f32x4 fzero = {0.f, 0.f, 0.f, 0.f};
#pragma unroll
  for (int mi = 0; mi < 4; ++mi)
#pragma unroll
    for (int ni = 0; ni < 4; ++ni) acc[mi][ni] = fzero;

  const int s_row = tid >> 3;
  const int s_cc  = tid & 7;
  const int NT = DM / 64;  // 16

  {
#pragma unroll
    for (int n = 0; n < 2; ++n) {
      int row = n * 64 + s_row;
      gload16(A + (size_t)(i0 + row) * DM + ((s_cc ^ (row & 7)) << 3),
              lA + n * 4096 + tid * 8);
    }
#pragma unroll
    for (int n = 0; n < 4; ++n) {
      int row = n * 64 + s_row;
      gload16(W + (size_t)(o0 + row) * DM + ((s_cc ^ (row & 7)) << 3),
              lB + n * 4096 + tid * 8);
    }
  }
  asm volatile("s_waitcnt vmcnt(0)" ::: "memory");
  __syncthreads();

  for (int t = 0; t < NT; ++t) {
    const int cur = t & 1;
    if (t + 1 < NT) {
      const int k0 = (t + 1) * 64;
      const int nxt = cur ^ 1;
#pragma unroll
      for (int n = 0; n < 2; ++n) {
        int row = n * 64 + s_row;
        gload16(A + (size_t)(i0 + row) * DM + k0 + ((s_cc ^ (row & 7)) << 3),
                lA + nxt * 8192 + n * 4096 + tid * 8);
      }
#pragma unroll
      for (int n = 0; n < 4; ++n) {
        int row = n * 64 + s_row;
        gload16(W + (size_t)(o0 + row) * DM + k0 + ((s_cc ^ (row & 7)) << 3),
                lB + nxt * 16384 + n * 4096 + tid * 8);
      }
    }

    const __bf16* cA = lA + cur * 8192;
    const __bf16* cB = lB + cur * 16384;

    bf16x8 af[4][2], bf_[2][2];
#pragma unroll
    for (int mi = 0; mi < 4; ++mi)
#pragma unroll
      for (int ks = 0; ks < 2; ++ks) {
        int row = wr * 64 + mi * 16 + lr;
        int chunk = (ks * 4 + lg) ^ (row & 7);
        af[mi][ks] = *(const bf16x8*)(cA + row * 64 + chunk * 8);
      }
#pragma unroll
    for (int ni = 0; ni < 2; ++ni)
#pragma unroll
      for (int ks = 0; ks < 2; ++ks) {
        int row = wc * 64 + ni * 16 + lr;
        int chunk = (ks * 4 + lg) ^ (row & 7);
        bf_[ni][ks] = *(const bf16x8*)(cB + row * 64 + chunk * 8);
      }
    __builtin_amdgcn_s_setprio(1);
#pragma unroll
    for (int mi = 0; mi < 4; ++mi)
#pragma unroll
      for (int ni = 0; ni < 2; ++ni)
#pragma unroll
        for (int ks = 0; ks < 2; ++ks)
          acc[mi][ni] = __builtin_amdgcn_mfma_f32_16x16x32_bf16(
              af[mi][ks], bf_[ni][ks], acc[mi][ni], 0, 0, 0);
    __builtin_amdgcn_s_setprio(0);

#pragma unroll
    for (int ni = 0; ni < 2; ++ni)
#pragma unroll
      for (int ks = 0; ks < 2; ++ks) {
        int row = wc * 64 + (ni + 2) * 16 + lr;
        int chunk = (ks * 4 + lg) ^ (row & 7);
        bf_[ni][ks] = *(const bf16x8*)(cB + row * 64 + chunk * 8);
      }
    __builtin_amdgcn_s_setprio(1);
#pragma unroll
    for (int mi = 0; mi < 4; ++mi)
#pragma unroll
      for (int ni = 0; ni < 2; ++ni)
#pragma unroll
        for (int ks = 0; ks < 2; ++ks)
          acc[mi][ni + 2] = __builtin_amdgcn_mfma_f32_16x16x32_bf16(
              af[mi][ks], bf_[ni][ks], acc[mi][ni + 2], 0, 0, 0);
    __builtin_amdgcn_s_setprio(0);

    if (t + 1 < NT) {
      asm volatile("s_waitcnt vmcnt(0)" ::: "memory");
      __syncthreads();
    }
  }

#pragma unroll
  for (int ni = 0; ni < 4; ++ni) {
    int col = o0 + wc * 64 + ni * 16 + lr;
    float bb = bias[col];
#pragma unroll
    for (int mi = 0; mi < 4; ++mi) {
      int row = i0 + wr * 64 + mi * 16 + lg * 4;
#pragma unroll
      for (int r = 0; r < 4; ++r)
        C[(size_t)(row + r) * DM + col] = (OUT_T)(acc[mi][ni][r] + bb);
    }
  }
}

// Output GEMM: grid 256 = 64 mi * 4 ni (exactly 1 block/CU), XCD-grouped.
__global__ __launch_bounds__(512, 2) void gemm_out_kernel(
    const __bf16* __restrict__ A, const __bf16* __restrict__ W,
    const float* __restrict__ bias, float* __restrict__ C) {
  __shared__ __align__(16) __bf16 lA[2 * 128 * 64];
  __shared__ __align__(16) __bf16 lB[2 * 256 * 64];
  const int flat = blockIdx.x;
  const int xcd = flat & 7, idx = flat >> 3;       // idx 0..31
  const int mi = xcd * 8 + (idx & 7);              // 0..63
  const int ni = idx >> 3;                         // 0..3
  gemm_body2<float>(A, W, bias, C, mi * 128, ni * 256, lA, lB);
}

// ---------------- pass B: column sums c[k] = sum_{q>=k} exp(s[q,k]); VT = V^T / c ----------------
// flat grid 1024; XCD-grouped; k-tile pairing {bx, 31-bx} -> constant work.
__global__ __launch_bounds__(256) void colstats_kernel(
    const __bf16* __restrict__ Q, const __bf16* __restrict__ K,
    const __bf16* __restrict__ V, __bf16* __restrict__ VT) {
  const int flat = blockIdx.x;
  const int wid = (flat & 7) * 128 + (flat >> 3);  // 0..1023
  const int g = wid >> 4, bx = wid & 15;
  const int h = g & 15, b = g >> 4;
  const int tid = threadIdx.x;
  const int w = tid >> 6, l = tid & 63, lr = l & 15, lg = l >> 4;
  const size_t base = (size_t)b * TSEQ * DM + (size_t)h * HD;

  __shared__ float part[4][64];
  __shared__ float invc[64];

  for (int ph = 0; ph < 2; ++ph) {
    const int kt = ph ? (31 - bx) : bx;
    const int k0 = kt * 64;

    bf16x8 kf[4][2];
#pragma unroll
    for (int ct = 0; ct < 4; ++ct)
#pragma unroll
      for (int ks = 0; ks < 2; ++ks)
        kf[ct][ks] = *(const bf16x8*)(K + base + (size_t)(k0 + ct * 16 + lr) * DM +
                                      ks * 32 + lg * 8);

    float csum[4] = {0.f, 0.f, 0.f, 0.f};
    const int nchunks = (TSEQ - k0) >> 4;  // >= 4 always
    for (int jj = w; jj < nchunks; jj += 4) {
      int qrow = k0 + jj * 16;
      bf16x8 a0 = *(const bf16x8*)(Q + base + (size_t)(qrow + lr) * DM + lg * 8);
      bf16x8 a1 = *(const bf16x8*)(Q + base + (size_t)(qrow + lr) * DM + 32 + lg * 8);
      const bool interior = (jj >= 4);  // whole chunk strictly below diagonal band
#pragma unroll
      for (int ct = 0; ct < 4; ++ct) {
        f32x4 s = {0.f, 0.f, 0.f, 0.f};
        s = __builtin_amdgcn_mfma_f32_16x16x32_bf16(a0, kf[ct][0], s, 0, 0, 0);
        s = __builtin_amdgcn_mfma_f32_16x16x32_bf16(a1, kf[ct][1], s, 0, 0, 0);
        if (interior) {
#pragma unroll
          for (int r = 0; r < 4; ++r) csum[ct] += __builtin_amdgcn_exp2f(s[r] * SCL);
        } else {
#pragma unroll
          for (int r = 0; r < 4; ++r) {
            int ql = jj * 16 + lg * 4 + r;
            int kl = ct * 16 + lr;
            float e = __builtin_amdgcn_exp2f(s[r] * SCL);
            csum[ct] += (ql >= kl) ? e : 0.f;
          }
        }
      }
    }

#pragma unroll
    for (int ct = 0; ct < 4; ++ct) {
      csum[ct] += __shfl_xor(csum[ct], 16, 64);
      csum[ct] += __shfl_xor(csum[ct], 32, 64);
    }

    if (l < 16) {
#pragma unroll
      for (int ct = 0; ct < 4; ++ct) part[w][ct * 16 + l] = csum[ct];
    }
    __syncthreads();
    if (tid < 64) {
      float c = part[0][tid] + part[1][tid] + part[2][tid] + part[3][tid];
      invc[tid] = 1.0f / c;
    }
    __syncthreads();

    // VT[b,h][d][k] = V[k][d] * invc ; thread t: d = t>>2, k-cols (t&3)*16..+15
    const int d = tid >> 2, gq = tid & 3;
    size_t vtb = (((size_t)(b * NH + h)) * HD + d) * TSEQ + k0 + gq * 16;
#pragma unroll
    for (int kc = 0; kc < 16; kc += 2) {
      int kl = gq * 16 + kc;
      float v0 = (float)V[base + (size_t)(k0 + kl) * DM + d] * invc[kl];
      float v1 = (float)V[base + (size_t)(k0 + kl + 1) * DM + d] * invc[kl + 1];
      bf16x2 o; o[0] = (__bf16)v0; o[1] = (__bf16)v1;
      *(bf16x2*)(VT + vtb + kc) = o;
    }
    __syncthreads();  // part/invc reuse safety across phases
  }
}

// XOR swizzle (involution) on element index of a [64][64] bf16 tile
__device__ __forceinline__ int swz(int e) { return e ^ (((e >> 6) & 7) << 3); }

// ---------------- pass C (FUSED): both q-tiles {31-bx, bx} in ONE K-loop ----------------
// Single-buffered (TLP covers latency: 39KB LDS -> 4 blocks/CU = 16 waves).
// Per staged K-tile: kb8/vb8 read ONCE, feed both tiles' MFMAs (28 DS : 32 MFMA
// for kt<=bx vs 44:32 as two passes); staging serial-points 33 -> 32-bx.
__global__ __launch_bounds__(256, 4) void ctx_kernel(
    const __bf16* __restrict__ Q, const __bf16* __restrict__ K,
    const __bf16* __restrict__ VT, __bf16* __restrict__ CTX) {
  __shared__ __align__(16) __bf16 lK[4096];
  __shared__ __align__(16) __bf16 lV[4096];
  __shared__ __align__(16) __bf16 lP[8][16 * 88];   // [wave + 4*tile]
  const int flat = blockIdx.x;
  const int wid = (flat & 7) * 128 + (flat >> 3);  // 0..1023
  const int g = wid >> 4, bx = wid & 15;
  const int h = g & 15, b = g >> 4;
  const int tid = threadIdx.x;
  const int w = tid >> 6, l = tid & 63, lr = l & 15, lg = l >> 4;
  const size_t base = (size_t)b * TSEQ * DM + (size_t)h * HD;
  const size_t vtb = ((size_t)(b * NH + h)) * HD * TSEQ;
  __bf16* pw1 = &lP[w][0];
  __bf16* pw2 = &lP[w + 4][0];

  const int qt1 = 31 - bx, qt2 = bx;   // qt1 >= 16 > qt2 always
  const int q01 = qt1 * 64, q02 = qt2 * 64;

  // gload source decomposition: LDS element e = n*2048 + w*512 + l*8
  // -> tile row = n*32 + srow, source col pre-swizzled by (row&7)
  const int srow = w * 8 + (l >> 3);
  const int scol = (((l & 7) ^ (l >> 3)) << 3);

  bf16x8 qf1[2], qf2[2];
#pragma unroll
  for (int ks = 0; ks < 2; ++ks) {
    qf1[ks] = *(const bf16x8*)(Q + base + (size_t)(q01 + w * 16 + lr) * DM + ks * 32 + lg * 8);
    qf2[ks] = *(const bf16x8*)(Q + base + (size_t)(q02 + w * 16 + lr) * DM + ks * 32 + lg * 8);
  }

  f32x4 acc1[4], acc2[4];
  const f32x4 fzero = {0.f, 0.f, 0.f, 0.f};
#pragma unroll
  for (int dt = 0; dt < 4; ++dt) { acc1[dt] = fzero; acc2[dt] = fzero; }

  for (int kt = 0; kt <= qt1; ++kt) {
    const int k0 = kt * 64;
    const bool two = (kt <= qt2);
    __syncthreads();   // prior iter's LDS reads done before overwrite
#pragma unroll
    for (int n = 0; n < 2; ++n) {
      gload16(K + base + (size_t)(k0 + n * 32 + srow) * DM + scol,
              lK + n * 2048 + w * 512);
      gload16(VT + vtb + (size_t)(n * 32 + srow) * TSEQ + k0 + scol,
              lV + n * 2048 + w * 512);
    }
    asm volatile("s_waitcnt vmcnt(0)" ::: "memory");
    __syncthreads();

    const bool diag1 = (kt == qt1), diag2 = (kt == qt2);
#pragma unroll
    for (int ct = 0; ct < 4; ++ct) {
      bf16x8 kb[2];
#pragma unroll
      for (int ks = 0; ks < 2; ++ks) {
        int e = (ct * 16 + lr) * 64 + ks * 32 + lg * 8;
        kb[ks] = *(const bf16x8*)(lK + swz(e));
      }
      // tile 1 (qt1): swapped QK -> lane lr = q, lg*4+r = k
      {
        f32x4 s = {0.f, 0.f, 0.f, 0.f};
        s = __builtin_amdgcn_mfma_f32_16x16x32_bf16(kb[0], qf1[0], s, 0, 0, 0);
        s = __builtin_amdgcn_mfma_f32_16x16x32_bf16(kb[1], qf1[1], s, 0, 0, 0);
        bf16x4 pk;
        if (diag1) {
#pragma unroll
          for (int r = 0; r < 4; ++r) {
            int ql = w * 16 + lr, kl = ct * 16 + lg * 4 + r;
            pk[r] = (__bf16)((ql >= kl) ? __builtin_amdgcn_exp2f(s[r] * SCL) : 0.f);
          }
        } else {
#pragma unroll
          for (int r = 0; r < 4; ++r)
            pk[r] = (__bf16)__builtin_amdgcn_exp2f(s[r] * SCL);
        }
        *(bf16x4*)(pw1 + lr * 88 + ct * 16 + lg * 4) = pk;
      }
      if (two) {
        f32x4 s = {0.f, 0.f, 0.f, 0.f};
        s = __builtin_amdgcn_mfma_f32_16x16x32_bf16(kb[0], qf2[0], s, 0, 0, 0);
        s = __builtin_amdgcn_mfma_f32_16x16x32_bf16(kb[1], qf2[1], s, 0, 0, 0);
        bf16x4 pk;
        if (diag2) {
#pragma unroll
          for (int r = 0; r < 4; ++r) {
            int ql = w * 16 + lr, kl = ct * 16 + lg * 4 + r;
            pk[r] = (__bf16)((ql >= kl) ? __builtin_amdgcn_exp2f(s[r] * SCL) : 0.f);
          }
        } else {
#pragma unroll
          for (int r = 0; r < 4; ++r)
            pk[r] = (__bf16)__builtin_amdgcn_exp2f(s[r] * SCL);
        }
        *(bf16x4*)(pw2 + lr * 88 + ct * 16 + lg * 4) = pk;
      }
    }
    asm volatile("" ::: "memory");  // same-wave DS in-order: P writes before reads

    bf16x8 pa1[2], pa2[2];
#pragma unroll
    for (int ks = 0; ks < 2; ++ks)
      pa1[ks] = *(const bf16x8*)(pw1 + lr * 88 + ks * 32 + lg * 8);
    if (two) {
#pragma unroll
      for (int ks = 0; ks < 2; ++ks)
        pa2[ks] = *(const bf16x8*)(pw2 + lr * 88 + ks * 32 + lg * 8);
    }
#pragma unroll
    for (int dt = 0; dt < 4; ++dt) {
#pragma unroll
      for (int ks = 0; ks < 2; ++ks) {
        int e = (dt * 16 + lr) * 64 + ks * 32 + lg * 8;
        bf16x8 vb8 = *(const bf16x8*)(lV + swz(e));   // shared by both tiles
        acc1[dt] = __builtin_amdgcn_mfma_f32_16x16x32_bf16(pa1[ks], vb8, acc1[dt], 0, 0, 0);
        if (two)
          acc2[dt] = __builtin_amdgcn_mfma_f32_16x16x32_bf16(pa2[ks], vb8, acc2[dt], 0, 0, 0);
      }
    }
  }

#pragma unroll
  for (int dt = 0; dt < 4; ++dt)
#pragma unroll
    for (int r = 0; r < 4; ++r) {
      CTX[base + (size_t)(q01 + w * 16 + lg * 4 + r) * DM + dt * 16 + lr] = (__bf16)acc1[dt][r];
      CTX[base + (size_t)(q02 + w * 16 + lg * 4 + r) * DM + dt * 16 + lr] = (__bf16)acc2[dt][r];
    }
}

extern "C" void kernel_launch(void* const* d_in, const int* in_sizes, int n_in,
                              void* d_out, int out_size, void* d_ws, size_t ws_size,
                              hipStream_t stream) {
  const float* q  = (const float*)d_in[0];
  const float* Wq = (const float*)d_in[3];
  const float* bq = (const float*)d_in[4];
  const float* Wk = (const float*)d_in[5];
  const float* bk = (const float*)d_in[6];
  const float* Wv = (const float*)d_in[7];
  const float* bv = (const float*)d_in[8];
  const float* Wo = (const float*)d_in[9];
  const float* bo = (const float*)d_in[10];
  float* out = (float*)d_out;

  const size_t NTOK = (size_t)BATCH * TSEQ;  // 8192
  char* ws = (char*)d_ws;
  __bf16* qb  = (__bf16*)ws; ws += NTOK * DM * 2;   // reused as CTX after QKV GEMMs
  __bf16* Wqb = (__bf16*)ws; ws += (size_t)DM * DM * 2;
  __bf16* Wkb = (__bf16*)ws; ws += (size_t)DM * DM * 2;
  __bf16* Wvb = (__bf16*)ws; ws += (size_t)DM * DM * 2;
  __bf16* Wob = (__bf16*)ws; ws += (size_t)DM * DM * 2;
  __bf16* Qp  = (__bf16*)ws; ws += NTOK * DM * 2;
  __bf16* Kp  = (__bf16*)ws; ws += NTOK * DM * 2;
  __bf16* Vp  = (__bf16*)ws; ws += NTOK * DM * 2;
  __bf16* VT  = (__bf16*)ws; ws += (size_t)BATCH * NH * HD * TSEQ * 2;
  __bf16* CTX = qb;  // qb dead after the QKV GEMMs

  const int nq4 = (int)(NTOK * DM / 4);
  const int nw4 = DM * DM / 4;
  cvt_kernel<<<(nq4 + 255) / 256, 256, 0, stream>>>(q, qb, nq4);
  cvt4_kernel<<<dim3((nw4 + 255) / 256, 4), 256, 0, stream>>>(
      Wq, Wk, Wv, Wo, Wqb, Wkb, Wvb, Wob, nw4);

  gemm_qkv_kernel<<<384, 512, 0, stream>>>(qb, Wqb, Wkb, Wvb, bq, bk, bv,
                                           Qp, Kp, Vp);

  colstats_kernel<<<1024, 256, 0, stream>>>(Qp, Kp, Vp, VT);
  ctx_kernel<<<1024, 256, 0, stream>>>(Qp, Kp, VT, CTX);

  gemm_out_kernel<<<256, 512, 0, stream>>>(CTX, Wob, bo, out);
}